// Round 2
// baseline (400.077 us; speedup 1.0000x reference)
//
#include <hip/hip_runtime.h>

#define B_SZ  1024
#define NSEQ  512
#define D_INP 30
#define H     64
#define MB    16
#define TCH   8
#define L2E   1.4426950408889634f

typedef short s16x8 __attribute__((ext_vector_type(8)));
typedef float f32x4 __attribute__((ext_vector_type(4)));

#if __has_builtin(__builtin_amdgcn_exp2f)
#define EXP2(x) __builtin_amdgcn_exp2f(x)
#else
#define EXP2(x) exp2f(x)
#endif

__device__ __forceinline__ float rcp_f(float v) { return __builtin_amdgcn_rcpf(v); }

__device__ __forceinline__ f32x4 mfma16(s16x8 a, s16x8 b, f32x4 c) {
  return __builtin_amdgcn_mfma_f32_16x16x32_bf16(a, b, c, 0, 0, 0);
}

__device__ __forceinline__ short bf16_rne(float f) {
  unsigned u = __float_as_uint(f);
  unsigned r = (u + 0x7FFFu + ((u >> 16) & 1u)) >> 16;
  return (short)r;
}

__device__ __forceinline__ s16x8 rne8(const float* f) {
  s16x8 o;
#pragma unroll
  for (int i = 0; i < 8; ++i) o[i] = bf16_rne(f[i]);
  return o;
}

__device__ __forceinline__ void split8(const float* f, s16x8& hi, s16x8& lo) {
#pragma unroll
  for (int i = 0; i < 8; ++i) {
    unsigned ub = __float_as_uint(f[i]);
    hi[i] = (short)(ub >> 16);
    float hf = __uint_as_float(ub & 0xFFFF0000u);
    float lf = f[i] - hf;
    lo[i] = (short)(__float_as_uint(lf) >> 16);
  }
}

// lgkmcnt-only barrier: LDS ordering preserved, global loads stay in flight.
__device__ __forceinline__ void wg_barrier() {
  asm volatile("s_waitcnt lgkmcnt(0)" ::: "memory");
  __builtin_amdgcn_s_barrier();
  asm volatile("" ::: "memory");
}

// ---------------------------------------------------------------------------
// Kernel A: fold FC into the input-side gate GEMM (fp32).
// ---------------------------------------------------------------------------
__global__ __launch_bounds__(256) void prep_kernel(
    const float* __restrict__ W_fc, const float* __restrict__ b_fc,
    const float* __restrict__ W_ih, const float* __restrict__ b_ih,
    const float* __restrict__ b_hh,
    float* __restrict__ wsW, float* __restrict__ wsB) {
  __shared__ float fc[H * D_INP];
  __shared__ float bfc[H];
  const int u = threadIdx.x;
  for (int i = u; i < H * D_INP; i += 256) fc[i] = W_fc[i];
  if (u < H) bfc[u] = b_fc[u];
  __syncthreads();

  float wih[H];
#pragma unroll
  for (int i = 0; i < H; ++i) wih[i] = W_ih[u * H + i];

  for (int k = 0; k < D_INP; ++k) {
    float s = 0.f;
#pragma unroll
    for (int i = 0; i < H; ++i) s = fmaf(wih[i], fc[i * D_INP + k], s);
    wsW[u * 32 + k] = s;
  }
  wsW[u * 32 + 30] = 0.f;
  wsW[u * 32 + 31] = 0.f;

  float bb = b_ih[u] + b_hh[u];
#pragma unroll
  for (int i = 0; i < H; ++i) bb = fmaf(wih[i], bfc[i], bb);
  wsB[u] = bb;
}

// ---------------------------------------------------------------------------
// Kernel B: MFMA LSTM, 64 blocks x 512 threads (8 waves, 2/SIMD).
// TRANSPOSED gate compute: G^T = W^T * h^T (operand-swapped MFMA; per-lane
// fragment data is identical to the non-transposed form, only the call's
// operand order changes). D-frag: col = batch (lane&15), row = gate-unit
// (q*4+r).
// All 8 waves symmetric: pair (2c, 2c+1) duplicates col-block c's gate
// MFMAs; wave p=w&1 activates only D-rows {2p, 2p+1} (half the
// transcendental issue per wave; the pair's stalls overlap with the
// partner's issue on the neighboring SIMD). Cell state in registers.
// h-write: one b32 per lane (2 contiguous units). One barrier per step.
// Staging: each wave stages chunk-slot w. Logit: rotating wave (t&7),
// reusing its already-loaded h-frags. vmcnt never drained in-loop.
// Numerics identical to previous round (same products, same order).
// ---------------------------------------------------------------------------
__global__ __launch_bounds__(512, 2) void lstm_mfma(
    const float* __restrict__ x, const float* __restrict__ W_hh,
    const float* __restrict__ wsW, const float* __restrict__ wsB,
    const float* __restrict__ W_last, float* __restrict__ out) {

  __shared__ short xa[2][TCH][64][8];              // 16 KB
  __shared__ short hpl[2][MB][72];                 // 4.6 KB
  __shared__ float logitsT[NSEQ + 1][MB];          // 32.8 KB

  const int u   = threadIdx.x;    // 0..511
  const int w   = u >> 6;         // wave 0..7
  const int l   = u & 63;
  const int low = l & 15;
  const int q   = l >> 4;
  const int b0  = blockIdx.x * MB;
  const int c   = w >> 1;         // col-block 0..3 (units 16c..16c+16)
  const int p   = w & 1;          // row-pair select: rows {2p, 2p+1}

  // ---- B-frags for all 4 gates of col-block c (A operand = W^T) ----
  // gate order: 0=i, 1=f, 2=g, 3=o ; unit n = 64*g + 16c + low.
  s16x8 whh[4][2], wcb[4];
  f32x4 bias4[4];
  s16x8 wl_h[2], wl_l[2];
  {
    float tmp[8];
#pragma unroll
    for (int g2 = 0; g2 < 4; ++g2) {
      const int n = 64 * g2 + 16 * c + low;
      const float sc = (g2 == 2) ? (2.0f * L2E) : L2E;
#pragma unroll
      for (int kt = 0; kt < 2; ++kt) {
        const float* pp = W_hh + n * H + kt * 32 + q * 8;
#pragma unroll
        for (int j = 0; j < 8; ++j) tmp[j] = pp[j] * sc;
        whh[g2][kt] = rne8(tmp);
      }
      const float* pw = wsW + n * 32 + q * 8;
#pragma unroll
      for (int j = 0; j < 8; ++j) tmp[j] = pw[j] * sc;
      wcb[g2] = rne8(tmp);
#pragma unroll
      for (int r = 0; r < 4; ++r)
        bias4[g2][r] = wsB[64 * g2 + 16 * c + q * 4 + r] * sc;
    }
#pragma unroll
    for (int kt = 0; kt < 2; ++kt) {
#pragma unroll
      for (int j = 0; j < 8; ++j)
        tmp[j] = (low == 0) ? W_last[kt * 32 + q * 8 + j] : 0.0f;
      split8(tmp, wl_h[kt], wl_l[kt]);
    }
  }

  // zero h planes
  for (int i = u; i < 2 * MB * 72 / 2; i += 512) ((int*)hpl)[i] = 0;

  // ---- x staging: wave w stages chunk-slot w ----
  const float* xrow = x + (size_t)(b0 + low) * NSEQ * D_INP + q * 8;
  float pf[8];
  auto stage_load = [&](int t0) {
    const float* pp = xrow + (size_t)(t0 + w) * D_INP;
    float2 v0 = *(const float2*)(pp);
    float2 v1 = *(const float2*)(pp + 2);
    float2 v2 = *(const float2*)(pp + 4);
    float2 v3 = (q < 3) ? *(const float2*)(pp + 6) : make_float2(0.f, 0.f);
    pf[0] = v0.x; pf[1] = v0.y; pf[2] = v1.x; pf[3] = v1.y;
    pf[4] = v2.x; pf[5] = v2.y; pf[6] = v3.x; pf[7] = v3.y;
  };
  auto stage_write = [&](int buf) {
    *(s16x8*)&xa[buf][w][l][0] = rne8(pf);
  };

  stage_load(0);
  stage_write(0);
  __syncthreads();

  // xacc prefetch for t = 0 (transposed: W as A, x^T as B)
  f32x4 xacc[4];
  {
    s16x8 xah = *(const s16x8*)&xa[0][0][l][0];
#pragma unroll
    for (int g2 = 0; g2 < 4; ++g2)
      xacc[g2] = mfma16(wcb[g2], xah, bias4[g2]);
  }

  float c2_0 = 0.f, c2_1 = 0.f;   // cell state for the wave's two rows

#define ACT(R, CREF, HV)                                                   \
  {                                                                        \
    float gi = rcp_f(1.0f + EXP2(-acc[0][R]));                             \
    float gf = rcp_f(1.0f + EXP2(-acc[1][R]));                             \
    float gg = 1.0f - 2.0f * rcp_f(1.0f + EXP2(acc[2][R]));                \
    float go = rcp_f(1.0f + EXP2(-acc[3][R]));                             \
    float cc = fmaf(gf, CREF, gi * gg);                                    \
    CREF = cc;                                                             \
    float hh2 = go * (1.0f - 2.0f * rcp_f(1.0f + EXP2(cc * (2.0f * L2E))));\
    HV = bf16_rne(hh2);                                                    \
  }

  for (int t = 0; t < NSEQ; ++t) {
    const int tt = t & (TCH - 1);
    const int cb = (t >> 3) & 1;

    // ---- h^T B-frags (same per-lane data as before) ----
    const short* hp = &hpl[(t + 1) & 1][low][0];
    s16x8 ah0 = *(const s16x8*)(hp + q * 8);
    s16x8 ah1 = *(const s16x8*)(hp + 32 + q * 8);

    f32x4 acc[4];
#pragma unroll
    for (int g2 = 0; g2 < 4; ++g2) acc[g2] = mfma16(whh[g2][0], ah0, xacc[g2]);
#pragma unroll
    for (int g2 = 0; g2 < 4; ++g2) acc[g2] = mfma16(whh[g2][1], ah1, acc[g2]);

    // prefetch next timestep's x-side acc (independent of h)
    if (t + 1 < NSEQ) {
      const int t1 = t + 1;
      s16x8 xah = *(const s16x8*)&xa[(t1 >> 3) & 1][t1 & 7][l][0];
#pragma unroll
      for (int g2 = 0; g2 < 4; ++g2)
        xacc[g2] = mfma16(wcb[g2], xah, bias4[g2]);
    }

    // rotating logit of h_{t-1}: reuses this step's h-frags
    if (w == (t & 7)) {
      f32x4 aL = {0.f, 0.f, 0.f, 0.f};
      aL = mfma16(wl_h[0], ah0, aL);
      aL = mfma16(wl_h[1], ah1, aL);
      f32x4 bL = {0.f, 0.f, 0.f, 0.f};
      bL = mfma16(wl_l[0], ah0, bL);
      bL = mfma16(wl_l[1], ah1, bL);
      aL = aL + bL;
      if (q == 0) logitsT[t][low] = aL[0];
    }

    // staging (all waves, slot w)
    if (tt == 0 && t + TCH < NSEQ) stage_load(t + TCH);
    if (tt == 4 && t + 4 < NSEQ) stage_write(cb ^ 1);

    // ---- activations for this wave's row pair {2p, 2p+1} ----
    short hv0, hv1;
    if (p == 0) {
      ACT(0, c2_0, hv0);
      ACT(1, c2_1, hv1);
    } else {
      ACT(2, c2_0, hv0);
      ACT(3, c2_1, hv1);
    }
    // one b32 write: batch=low, units 16c + q*4 + 2p + {0,1}
    int pk = ((int)(unsigned short)hv0) | ((int)hv1 << 16);
    *(int*)&hpl[t & 1][low][16 * c + q * 4 + 2 * p] = pk;

    wg_barrier();
  }
#undef ACT

  // final logit from h_511 (in plane 1)
  if (w == 0) {
    const short* hp = &hpl[1][low][0];
    s16x8 ah0 = *(const s16x8*)(hp + q * 8);
    s16x8 ah1 = *(const s16x8*)(hp + 32 + q * 8);
    f32x4 aL = {0.f, 0.f, 0.f, 0.f};
    aL = mfma16(wl_h[0], ah0, aL);
    aL = mfma16(wl_h[1], ah1, aL);
    f32x4 bL = {0.f, 0.f, 0.f, 0.f};
    bL = mfma16(wl_l[0], ah0, bL);
    bL = mfma16(wl_l[1], ah1, bL);
    aL = aL + bL;
    if (q == 0) logitsT[NSEQ][low] = aL[0];
  }
  __syncthreads();

  // ---- softmax over time (first 256 threads) ----
  if (u < 256) {
    const int m = u >> 4, li = u & 15;
    float lv[32];
    float mx = -3.0e38f;
#pragma unroll
    for (int s = 0; s < 32; ++s) {
      lv[s] = logitsT[1 + li + 16 * s][m];
      mx = fmaxf(mx, lv[s]);
    }
#pragma unroll
    for (int d = 1; d < 16; d <<= 1) mx = fmaxf(mx, __shfl_xor(mx, d, 16));
    float sum = 0.f;
#pragma unroll
    for (int s = 0; s < 32; ++s) { lv[s] = __expf(lv[s] - mx); sum += lv[s]; }
#pragma unroll
    for (int d = 1; d < 16; d <<= 1) sum += __shfl_xor(sum, d, 16);
    float inv = 1.0f / sum;
#pragma unroll
    for (int s = 0; s < 32; ++s)
      out[(size_t)(b0 + m) * NSEQ + li + 16 * s] = lv[s] * inv;
  }
}

// ---------------------------------------------------------------------------
extern "C" void kernel_launch(void* const* d_in, const int* in_sizes, int n_in,
                              void* d_out, int out_size, void* d_ws, size_t ws_size,
                              hipStream_t stream) {
  const float* x      = (const float*)d_in[0];
  const float* W_fc   = (const float*)d_in[1];
  const float* b_fc   = (const float*)d_in[2];
  const float* W_ih   = (const float*)d_in[3];
  const float* W_hh   = (const float*)d_in[4];
  const float* b_ih   = (const float*)d_in[5];
  const float* b_hh   = (const float*)d_in[6];
  const float* W_last = (const float*)d_in[7];
  // d_in[8] = b_last: cancels in softmax.

  float* out = (float*)d_out;
  float* wsW = (float*)d_ws;          // 256*32 floats
  float* wsB = wsW + 256 * 32;        // 256 floats

  prep_kernel<<<1, 256, 0, stream>>>(W_fc, b_fc, W_ih, b_ih, b_hh, wsW, wsB);
  lstm_mfma<<<B_SZ / MB, 512, 0, stream>>>(x, W_hh, wsW, wsB, W_last, out);
}

// Round 4
// 263.760 us; speedup vs baseline: 1.5168x; 1.5168x over previous
//
#include <hip/hip_runtime.h>

#define B_SZ  1024
#define NSEQ  512
#define D_INP 30
#define H     64
#define MB    4
#define TCH   8
#define L2E   1.4426950408889634f

typedef short s16x8 __attribute__((ext_vector_type(8)));
typedef float f32x4 __attribute__((ext_vector_type(4)));

#if __has_builtin(__builtin_amdgcn_exp2f)
#define EXP2(x) __builtin_amdgcn_exp2f(x)
#else
#define EXP2(x) exp2f(x)
#endif

__device__ __forceinline__ float rcp_f(float v) { return __builtin_amdgcn_rcpf(v); }

__device__ __forceinline__ f32x4 mfma16(s16x8 a, s16x8 b, f32x4 c) {
  return __builtin_amdgcn_mfma_f32_16x16x32_bf16(a, b, c, 0, 0, 0);
}

__device__ __forceinline__ short bf16_rne(float f) {
  unsigned u = __float_as_uint(f);
  unsigned r = (u + 0x7FFFu + ((u >> 16) & 1u)) >> 16;
  return (short)r;
}

__device__ __forceinline__ s16x8 rne8(const float* f) {
  s16x8 o;
#pragma unroll
  for (int i = 0; i < 8; ++i) o[i] = bf16_rne(f[i]);
  return o;
}

__device__ __forceinline__ void split8(const float* f, s16x8& hi, s16x8& lo) {
#pragma unroll
  for (int i = 0; i < 8; ++i) {
    unsigned ub = __float_as_uint(f[i]);
    hi[i] = (short)(ub >> 16);
    float hf = __uint_as_float(ub & 0xFFFF0000u);
    float lf = f[i] - hf;
    lo[i] = (short)(__float_as_uint(lf) >> 16);
  }
}

// lgkmcnt-only barrier: LDS ordering preserved, global loads stay in flight.
__device__ __forceinline__ void wg_barrier() {
  asm volatile("s_waitcnt lgkmcnt(0)" ::: "memory");
  __builtin_amdgcn_s_barrier();
  asm volatile("" ::: "memory");
}

// ---------------------------------------------------------------------------
// Kernel A: fold FC into the input-side gate GEMM (fp32).
// ---------------------------------------------------------------------------
__global__ __launch_bounds__(256) void prep_kernel(
    const float* __restrict__ W_fc, const float* __restrict__ b_fc,
    const float* __restrict__ W_ih, const float* __restrict__ b_ih,
    const float* __restrict__ b_hh,
    float* __restrict__ wsW, float* __restrict__ wsB) {
  __shared__ float fc[H * D_INP];
  __shared__ float bfc[H];
  const int u = threadIdx.x;
  for (int i = u; i < H * D_INP; i += 256) fc[i] = W_fc[i];
  if (u < H) bfc[u] = b_fc[u];
  __syncthreads();

  float wih[H];
#pragma unroll
  for (int i = 0; i < H; ++i) wih[i] = W_ih[u * H + i];

  for (int k = 0; k < D_INP; ++k) {
    float s = 0.f;
#pragma unroll
    for (int i = 0; i < H; ++i) s = fmaf(wih[i], fc[i * D_INP + k], s);
    wsW[u * 32 + k] = s;
  }
  wsW[u * 32 + 30] = 0.f;
  wsW[u * 32 + 31] = 0.f;

  float bb = b_ih[u] + b_hh[u];
#pragma unroll
  for (int i = 0; i < H; ++i) bb = fmaf(wih[i], bfc[i], bb);
  wsB[u] = bb;
}

// ---------------------------------------------------------------------------
// Kernel B: MFMA LSTM, 256 blocks x 512 threads (8 waves, 2/SIMD, 1 blk/CU).
// Round-1 structure (best: 234us) with MB=16 -> MB=4: batch b occupies MFMA
// row 4b (rows {0,4,8,12}), so the activation loop is uniformly r=0 for all
// 64 lanes -> transcendental issue per G wave drops 4x (40 -> 10 quarter-rate
// ops/step), cell state is one float, h-write one ds_write_b16. Unused A/D
// rows are zero-initialized and never written (zero products, no NaN).
// Waves 0-3 ("G"): wave cw owns units [16cw,16cw+16), computes all 4 gates.
//   x-side gate MFMAs prefetched one step ahead (off the h chain).
// Waves 4-7 ("S"): x staging (2 chunk-slots each) + rotating h->logit MFMAs.
// One barrier per step; vmcnt never drained in-loop.
// Numerics bit-identical to round 1 (same products, same order; live rows
// only remapped) -> absmax must stay 1.525879e-05.
// ---------------------------------------------------------------------------
__global__ __launch_bounds__(512, 2) void lstm_mfma(
    const float* __restrict__ x, const float* __restrict__ W_hh,
    const float* __restrict__ wsW, const float* __restrict__ wsB,
    const float* __restrict__ W_last, float* __restrict__ out) {

  __shared__ short xa[2][TCH][64][8];              // 16 KB
  __shared__ short hpl[2][16][72];                 // 4.6 KB
  __shared__ float logitsT[NSEQ + 1][MB];          // 8.2 KB

  const int u   = threadIdx.x;    // 0..511
  const int w   = u >> 6;         // wave 0..7
  const int l   = u & 63;
  const int low = l & 15;
  const int q   = l >> 4;
  const int b0  = blockIdx.x * MB;
  const bool isS = (w >= 4);
  const int cw  = w & 3;          // G: unit col-block 0..3 / S: stage-pair id

  // ---- G waves: B-frags for all 4 gates of col-block cw ----
  // gate order: 0=i, 1=f, 2=g, 3=o ; unit n = 64*g + 16*cw + low.
  s16x8 whh[4][2], wcb[4];
  float xb[4];
  s16x8 wl_h[2], wl_l[2];

  if (!isS) {
    float tmp[8];
#pragma unroll
    for (int g2 = 0; g2 < 4; ++g2) {
      const int n = 64 * g2 + 16 * cw + low;
      const float sc = (g2 == 2) ? (2.0f * L2E) : L2E;
#pragma unroll
      for (int kt = 0; kt < 2; ++kt) {
        const float* p = W_hh + n * H + kt * 32 + q * 8;
#pragma unroll
        for (int j = 0; j < 8; ++j) tmp[j] = p[j] * sc;
        whh[g2][kt] = rne8(tmp);
      }
      const float* pw = wsW + n * 32 + q * 8;
#pragma unroll
      for (int j = 0; j < 8; ++j) tmp[j] = pw[j] * sc;
      wcb[g2] = rne8(tmp);
      xb[g2] = wsB[n] * sc;
    }
  } else {
#pragma unroll
    for (int kt = 0; kt < 2; ++kt) {
      float tmp[8];
#pragma unroll
      for (int j = 0; j < 8; ++j)
        tmp[j] = (low == 0) ? W_last[kt * 32 + q * 8 + j] : 0.0f;
      split8(tmp, wl_h[kt], wl_l[kt]);
    }
  }

  // zero x staging + h planes (unused rows must be zero forever)
  for (int i = u; i < 2 * TCH * 64 * 8 / 2; i += 512) ((int*)xa)[i] = 0;
  for (int i = u; i < 2 * 16 * 72 / 2; i += 512) ((int*)hpl)[i] = 0;
  __syncthreads();

  // ---- S-wave x staging: wave cw handles chunk-slots 2cw, 2cw+1 ----
  // batch b sits in staging row 4b; only rows {0,4,8,12} are live.
  const int srow = l & 15, sq = l >> 4;
  const bool sact = (srow & 3) == 0;          // live row lanes
  const float* xrow = x + (size_t)(b0 + (srow >> 2)) * NSEQ * D_INP + sq * 8;
  float pf0[8], pf1[8];
  auto ld8 = [&](const float* p, float* pf) {
    float2 v0 = *(const float2*)(p);
    float2 v1 = *(const float2*)(p + 2);
    float2 v2 = *(const float2*)(p + 4);
    float2 v3 = (sq < 3) ? *(const float2*)(p + 6) : make_float2(0.f, 0.f);
    pf[0] = v0.x; pf[1] = v0.y; pf[2] = v1.x; pf[3] = v1.y;
    pf[4] = v2.x; pf[5] = v2.y; pf[6] = v3.x; pf[7] = v3.y;
  };
  auto stage_load = [&](int t0) {
    const float* p = xrow + (size_t)(t0 + 2 * cw) * D_INP;
    ld8(p, pf0);
    ld8(p + D_INP, pf1);
  };
  auto stage_write = [&](int buf) {
    if (sact) {
      *(s16x8*)&xa[buf][2 * cw][l][0] = rne8(pf0);
      *(s16x8*)&xa[buf][2 * cw + 1][l][0] = rne8(pf1);
    }
  };

  if (isS) { stage_load(0); stage_write(0); }
  __syncthreads();

  // xacc prefetch for t = 0
  f32x4 xacc[4];
  if (!isS) {
    s16x8 xah = *(const s16x8*)&xa[0][0][l][0];
#pragma unroll
    for (int g2 = 0; g2 < 4; ++g2) {
      f32x4 a = {xb[g2], xb[g2], xb[g2], xb[g2]};
      xacc[g2] = mfma16(xah, wcb[g2], a);
    }
  }

  float cst = 0.f;   // G waves: cell state (batch q, unit 16cw+low)

  for (int t = 0; t < NSEQ; ++t) {
    const int tt = t & (TCH - 1);
    const int cb = (t >> 3) & 1;
    if (!isS) {
      // ---- recurrence critical path ----
      const short* hp = &hpl[(t + 1) & 1][low][0];
      s16x8 ah0 = *(const s16x8*)(hp + q * 8);
      s16x8 ah1 = *(const s16x8*)(hp + 32 + q * 8);

      f32x4 acc[4];
#pragma unroll
      for (int g2 = 0; g2 < 4; ++g2) acc[g2] = mfma16(ah0, whh[g2][0], xacc[g2]);
#pragma unroll
      for (int g2 = 0; g2 < 4; ++g2) acc[g2] = mfma16(ah1, whh[g2][1], acc[g2]);

      // prefetch next timestep's x-side acc (independent of h)
      if (t + 1 < NSEQ) {
        const int t1 = t + 1;
        s16x8 xah = *(const s16x8*)&xa[(t1 >> 3) & 1][t1 & 7][l][0];
#pragma unroll
        for (int g2 = 0; g2 < 4; ++g2) {
          f32x4 a = {xb[g2], xb[g2], xb[g2], xb[g2]};
          xacc[g2] = mfma16(xah, wcb[g2], a);
        }
      }

      // ---- activation: single live row r=0 (batch q) ----
      float gi = rcp_f(1.0f + EXP2(-acc[0][0]));
      float gf = rcp_f(1.0f + EXP2(-acc[1][0]));
      float gg = 1.0f - 2.0f * rcp_f(1.0f + EXP2(acc[2][0]));
      float go = rcp_f(1.0f + EXP2(-acc[3][0]));
      float cc = fmaf(gf, cst, gi * gg);
      cst = cc;
      float h = go * (1.0f - 2.0f * rcp_f(1.0f + EXP2(cc * (2.0f * L2E))));
      hpl[t & 1][q * 4][16 * cw + low] = bf16_rne(h);
    } else {
      // ---- service waves: logit of h_{t-1} (rotating) + x staging ----
      if (cw == (t & 3)) {
        const short* hp = &hpl[(t + 1) & 1][low][0];
        s16x8 ah0 = *(const s16x8*)(hp + q * 8);
        s16x8 ah1 = *(const s16x8*)(hp + 32 + q * 8);
        f32x4 aL = {0.f, 0.f, 0.f, 0.f};
        aL = mfma16(ah0, wl_h[0], aL);
        aL = mfma16(ah1, wl_h[1], aL);
        f32x4 bL = {0.f, 0.f, 0.f, 0.f};
        bL = mfma16(ah0, wl_l[0], bL);
        bL = mfma16(ah1, wl_l[1], bL);
        aL = aL + bL;
        if (low == 0) logitsT[t][q] = aL[0];   // batch q at D row 4q, col 0
      }
      if (tt == 0 && t + TCH < NSEQ) stage_load(t + TCH);
      if (tt == 4 && t + 4 < NSEQ) stage_write(cb ^ 1);
    }
    wg_barrier();
  }

  // final logit from h_511 (in plane 1)
  if (w == 4) {
    const short* hp = &hpl[1][low][0];
    s16x8 ah0 = *(const s16x8*)(hp + q * 8);
    s16x8 ah1 = *(const s16x8*)(hp + 32 + q * 8);
    f32x4 aL = {0.f, 0.f, 0.f, 0.f};
    aL = mfma16(ah0, wl_h[0], aL);
    aL = mfma16(ah1, wl_h[1], aL);
    f32x4 bL = {0.f, 0.f, 0.f, 0.f};
    bL = mfma16(ah0, wl_l[0], bL);
    bL = mfma16(ah1, wl_l[1], bL);
    aL = aL + bL;
    if (low == 0) logitsT[NSEQ][q] = aL[0];
  }
  __syncthreads();

  // ---- softmax over time (first 64 threads; 4 batches x 16 lanes) ----
  if (u < 16 * MB) {
    const int m = u >> 4, li = u & 15;
    float lv[32];
    float mx = -3.0e38f;
#pragma unroll
    for (int s = 0; s < 32; ++s) {
      lv[s] = logitsT[1 + li + 16 * s][m];
      mx = fmaxf(mx, lv[s]);
    }
#pragma unroll
    for (int d = 1; d < 16; d <<= 1) mx = fmaxf(mx, __shfl_xor(mx, d, 16));
    float sum = 0.f;
#pragma unroll
    for (int s = 0; s < 32; ++s) { lv[s] = __expf(lv[s] - mx); sum += lv[s]; }
#pragma unroll
    for (int d = 1; d < 16; d <<= 1) sum += __shfl_xor(sum, d, 16);
    float inv = 1.0f / sum;
#pragma unroll
    for (int s = 0; s < 32; ++s)
      out[(size_t)(b0 + m) * NSEQ + li + 16 * s] = lv[s] * inv;
  }
}

// ---------------------------------------------------------------------------
extern "C" void kernel_launch(void* const* d_in, const int* in_sizes, int n_in,
                              void* d_out, int out_size, void* d_ws, size_t ws_size,
                              hipStream_t stream) {
  const float* x      = (const float*)d_in[0];
  const float* W_fc   = (const float*)d_in[1];
  const float* b_fc   = (const float*)d_in[2];
  const float* W_ih   = (const float*)d_in[3];
  const float* W_hh   = (const float*)d_in[4];
  const float* b_ih   = (const float*)d_in[5];
  const float* b_hh   = (const float*)d_in[6];
  const float* W_last = (const float*)d_in[7];
  // d_in[8] = b_last: cancels in softmax.

  float* out = (float*)d_out;
  float* wsW = (float*)d_ws;          // 256*32 floats
  float* wsB = wsW + 256 * 32;        // 256 floats

  prep_kernel<<<1, 256, 0, stream>>>(W_fc, b_fc, W_ih, b_ih, b_hh, wsW, wsB);
  lstm_mfma<<<B_SZ / MB, 512, 0, stream>>>(x, W_hh, wsW, wsB, W_last, out);
}